// Round 1
// baseline (462.596 us; speedup 1.0000x reference)
//
#include <hip/hip_runtime.h>
#include <hip/hip_bf16.h>

// Problem: out[n,o] = x[n,:] . W[o,:] + bias[o] + scale * sum_r (x[n,:].la[a,r,:]) * lb[a,o,:][r]
//          where a = lora_mapping[n]-1 (skip if mapping==0).
// Strategy: fold LoRA into the GEMM K-dim. Build bf16 Xe[16384,2176], We[2048,2176]
//   Xe[:,0:2048]=bf16(x); Xe[n,2048+(a*16+r)] = bf16(scale * x[n].la[a,r])  (one-hot in a)
//   We[:,0:2048]=bf16(W); We[o,2048+(a*16+r)] = bf16(lb[a,o,r])
// Then out = Xe @ We^T + bias — a single uniform bf16 MFMA GEMM, K=2176=34*64.

#define D_IN   2048
#define D_OUT  2048
#define NTOK   16384
#define RANK   16
#define NADAPT 8
#define KEXT   2176          // 2048 + 8*16
#define BM     128
#define BN     128
#define BK     64

typedef __attribute__((ext_vector_type(8))) __bf16 bf16x8;
typedef __attribute__((ext_vector_type(4))) float  f32x4;

__device__ inline unsigned short f2bf(float f) {
    unsigned u = __builtin_bit_cast(unsigned, f);
    u += 0x7fffu + ((u >> 16) & 1u);      // round-to-nearest-even
    return (unsigned short)(u >> 16);
}

// ---------------------------------------------------------------------------
// prep_x: one wave per token. Reads x row once (float4, coalesced), writes the
// bf16 row of Xe, computes the 16 LoRA-A dot products in fp32 with a wave
// butterfly reduction, writes the 128-wide one-hot extension.
// ---------------------------------------------------------------------------
__global__ void prep_x(const float4* __restrict__ x, const int* __restrict__ map,
                       const float4* __restrict__ lora_a, const float* __restrict__ scaling,
                       unsigned short* __restrict__ Xe) {
    int wave = threadIdx.x >> 6, lane = threadIdx.x & 63;
    int n = blockIdx.x * 4 + wave;                       // token id
    const float4* xr = x + (size_t)n * (D_IN / 4);
    unsigned short* xo = Xe + (size_t)n * KEXT;

    float4 xv[8];
#pragma unroll
    for (int j = 0; j < 8; ++j) {
        xv[j] = xr[j * 64 + lane];
        ushort4 s;
        s.x = f2bf(xv[j].x); s.y = f2bf(xv[j].y);
        s.z = f2bf(xv[j].z); s.w = f2bf(xv[j].w);
        *(ushort4*)(xo + (j * 64 + lane) * 4) = s;       // 8B coalesced store
    }

    int aid = map[n];                                    // 0 = no adapter (wave-uniform branch)
    int c0 = lane * 2;                                   // my 2 extension columns
    float myu0 = 0.f, myu1 = 0.f;
    int r0 = c0 & 15;
    if (aid > 0) {
        int a = aid - 1;
        float sc = scaling[a];
        const float4* lab = lora_a + (size_t)a * RANK * (D_IN / 4);
#pragma unroll
        for (int r = 0; r < RANK; ++r) {
            const float4* lar = lab + r * (D_IN / 4);
            float acc = 0.f;
#pragma unroll
            for (int j = 0; j < 8; ++j) {
                float4 lv = lar[j * 64 + lane];
                acc += xv[j].x * lv.x + xv[j].y * lv.y + xv[j].z * lv.z + xv[j].w * lv.w;
            }
#pragma unroll
            for (int m = 32; m >= 1; m >>= 1) acc += __shfl_xor(acc, m, 64);
            float uv = acc * sc;
            if (r == r0)     myu0 = uv;
            if (r == r0 + 1) myu1 = uv;
        }
    }
    ushort2 e; e.x = 0; e.y = 0;
    if (aid > 0 && (c0 >> 4) == (aid - 1)) { e.x = f2bf(myu0); e.y = f2bf(myu1); }
    *(ushort2*)(xo + D_IN + c0) = e;
}

// ---------------------------------------------------------------------------
// prep_w: one wave per output row. bf16(W row) + lb extension.
// ---------------------------------------------------------------------------
__global__ void prep_w(const float4* __restrict__ w, const float* __restrict__ lora_b,
                       unsigned short* __restrict__ We) {
    int wave = threadIdx.x >> 6, lane = threadIdx.x & 63;
    int o = blockIdx.x * 4 + wave;
    const float4* wr = w + (size_t)o * (D_IN / 4);
    unsigned short* wo = We + (size_t)o * KEXT;
#pragma unroll
    for (int j = 0; j < 8; ++j) {
        float4 v = wr[j * 64 + lane];
        ushort4 s;
        s.x = f2bf(v.x); s.y = f2bf(v.y); s.z = f2bf(v.z); s.w = f2bf(v.w);
        *(ushort4*)(wo + (j * 64 + lane) * 4) = s;
    }
    int c0 = lane * 2;
    int a = c0 >> 4, r = c0 & 15;                        // r even
    const float* src = lora_b + ((size_t)a * D_OUT + o) * RANK + r;
    ushort2 e; e.x = f2bf(src[0]); e.y = f2bf(src[1]);
    *(ushort2*)(wo + D_IN + c0) = e;
}

// ---------------------------------------------------------------------------
// Main GEMM: out[M=16384, N=2048] = Xe @ We^T + bias.  m97 structure:
// 128x128 tile, BK=64, 4 waves in 2x2, each wave 64x64 via 4x4 of 16x16x32
// bf16 MFMA, global_load_lds width=16 staging, XOR-swizzled LDS k-chunks
// (swizzle applied on the global source address so the wave-uniform LDS
// destination stays contiguous — required by global_load_lds semantics).
// ---------------------------------------------------------------------------
__global__ void gemm_fused(const unsigned short* __restrict__ Xe,
                           const unsigned short* __restrict__ We,
                           const float* __restrict__ bias,
                           float* __restrict__ out) {
    __shared__ unsigned short As[BM * BK];               // [128][64] bf16, 16 KB
    __shared__ unsigned short Bs[BN * BK];

    int t = threadIdx.x;
    int lane = t & 63, wave = t >> 6;
    // supertile swizzle: groups of 8 row-tiles x 16 col-tiles for L2 locality
    int g = blockIdx.x;
    int group = g >> 7, within = g & 127;
    int bm = group * 8 + (within & 7);                   // 0..127
    int bn = within >> 3;                                // 0..15

    int wm = wave >> 1, wn = wave & 1;                   // 2x2 wave grid
    f32x4 acc[4][4] = {};

    for (int k0 = 0; k0 < KEXT; k0 += BK) {
        __syncthreads();                                 // prev compute done
#pragma unroll
        for (int c = 0; c < 4; ++c) {
            int linear = (wave * 4 + c) * 64 + lane;     // 16B-chunk id within tile
            int row = linear >> 3;                       // 0..127
            int kc  = linear & 7;                        // 16B chunk within row
            int gc  = kc ^ (row & 7);                    // fetch swizzled source chunk
            const unsigned short* ga = Xe + (size_t)(bm * BM + row) * KEXT + k0 + gc * 8;
            __builtin_amdgcn_global_load_lds(
                (const __attribute__((address_space(1))) unsigned int*)ga,
                (__attribute__((address_space(3))) unsigned int*)(As + (wave * 4 + c) * 512),
                16, 0, 0);
            const unsigned short* gb = We + (size_t)(bn * BN + row) * KEXT + k0 + gc * 8;
            __builtin_amdgcn_global_load_lds(
                (const __attribute__((address_space(1))) unsigned int*)gb,
                (__attribute__((address_space(3))) unsigned int*)(Bs + (wave * 4 + c) * 512),
                16, 0, 0);
        }
        __syncthreads();                                 // staging visible (compiler drains vmcnt)
#pragma unroll
        for (int ks = 0; ks < 2; ++ks) {                 // two K=32 steps per BK=64
            bf16x8 af[4], bfr[4];
            int gchunk = ks * 4 + (lane >> 4);
            int sw = gchunk ^ (lane & 7);                // row&7 == lane&7 for 16-aligned tiles
#pragma unroll
            for (int i = 0; i < 4; ++i) {
                int rowA = wm * 64 + i * 16 + (lane & 15);
                af[i]  = *(const bf16x8*)(As + rowA * BK + sw * 8);
                int rowB = wn * 64 + i * 16 + (lane & 15);
                bfr[i] = *(const bf16x8*)(Bs + rowB * BK + sw * 8);
            }
#pragma unroll
            for (int i = 0; i < 4; ++i)
#pragma unroll
                for (int j = 0; j < 4; ++j)
                    acc[i][j] = __builtin_amdgcn_mfma_f32_16x16x32_bf16(af[i], bfr[j], acc[i][j], 0, 0, 0);
        }
    }

    // epilogue: C/D layout col=lane&15, row=(lane>>4)*4+reg  [m89-verified]
    int colq = lane & 15, rq = lane >> 4;
#pragma unroll
    for (int j = 0; j < 4; ++j) {
        int col = bn * BN + wn * 64 + j * 16 + colq;
        float bv = bias[col];
#pragma unroll
        for (int i = 0; i < 4; ++i) {
            int row0 = bm * BM + wm * 64 + i * 16 + rq * 4;
#pragma unroll
            for (int r = 0; r < 4; ++r)
                out[(size_t)(row0 + r) * D_OUT + col] = acc[i][j][r] + bv;
        }
    }
}

extern "C" void kernel_launch(void* const* d_in, const int* in_sizes, int n_in,
                              void* d_out, int out_size, void* d_ws, size_t ws_size,
                              hipStream_t stream) {
    (void)in_sizes; (void)n_in; (void)out_size; (void)ws_size;
    const float* x       = (const float*)d_in[0];
    const int*   map     = (const int*)d_in[1];
    const float* weight  = (const float*)d_in[2];
    const float* bias    = (const float*)d_in[3];
    const float* lora_a  = (const float*)d_in[4];
    const float* lora_b  = (const float*)d_in[5];
    const float* scaling = (const float*)d_in[6];
    float* out = (float*)d_out;

    unsigned short* Xe = (unsigned short*)d_ws;                    // 16384*2176*2 = 71.3 MB
    unsigned short* We = Xe + (size_t)NTOK * KEXT;                 // + 8.9 MB (16B aligned)

    prep_x<<<NTOK / 4, 256, 0, stream>>>((const float4*)x, map, (const float4*)lora_a, scaling, Xe);
    prep_w<<<D_OUT / 4, 256, 0, stream>>>((const float4*)weight, lora_b, We);
    gemm_fused<<<(NTOK / BM) * (D_OUT / BN), 256, 0, stream>>>(Xe, We, bias, out);
}